// Round 15
// baseline (223.157 us; speedup 1.0000x reference)
//
#include <hip/hip_runtime.h>

#define DD 64          // node embedding dim
#define RR 8           // num relations
#define KA 576         // (RR+1)*DD : agg rows 0..7 + x as "relation 8"
#define NT 18          // K steps = KA/32
#define NPART 8        // dst partitions ~ XCDs (blockIdx%8 round-robin)
#define ECH 2048       // edges per slice-block in partitioned kernels
#define TILE 32        // dsts per fused block (36.9KB LDS -> 4 blocks/CU)

typedef short bf16x8 __attribute__((ext_vector_type(8)));   // 8 bf16
typedef float f32x4  __attribute__((ext_vector_type(4)));

__device__ __forceinline__ float bf2f(unsigned short u) {
    union { unsigned u; float f; } c; c.u = ((unsigned)u) << 16; return c.f;
}
__device__ __forceinline__ unsigned short f2bf(float f) {
    union { float f; unsigned u; } c; c.f = f;
    unsigned u = c.u;
    u += 0x7FFF + ((u >> 16) & 1);      // round-to-nearest-even
    return (unsigned short)(u >> 16);
}

// ---------------------------------------------------------------------------
// x -> bf16 rows; row N is an all-zero pad row (targets of dummy pad edges).
// ---------------------------------------------------------------------------
__global__ void k_xcast(const float* __restrict__ x, unsigned short* __restrict__ xb,
                        int N)
{
    int i = blockIdx.x * 256 + threadIdx.x;              // quad index
    int total = (N + 1) * (DD / 4);
    if (i >= total) return;
    ushort4 o;
    if (i < N * (DD / 4)) {
        float4 f = ((const float4*)x)[i];
        o = make_ushort4(f2bf(f.x), f2bf(f.y), f2bf(f.z), f2bf(f.w));
    } else {
        o = make_ushort4(0, 0, 0, 0);
    }
    ((ushort4*)xb)[i] = o;
}

// ---------------------------------------------------------------------------
// Count + rank + edge echo fused (full-lane, 8-deep): 8 independent returning
// atomics in flight per thread. rr = rank | rel<<24. Echo of edge_index /
// edge_type piggybacks on the loads already needed here.
// ---------------------------------------------------------------------------
__global__ __launch_bounds__(256) void k_count_rank_echo(
    const int* __restrict__ ei, const int* __restrict__ et,
    int* __restrict__ cnt, unsigned* __restrict__ rr,
    float* __restrict__ out_ei, float* __restrict__ out_et, int E)
{
    const int base = blockIdx.x * ECH + threadIdx.x;
    int d[8], t[8], s[8], rk[8]; bool m[8];
    #pragma unroll
    for (int j = 0; j < 8; ++j) {
        int e = base + j * 256;
        m[j] = (e < E);
        d[j] = m[j] ? ei[E + e] : 0;
    }
    #pragma unroll
    for (int j = 0; j < 8; ++j) {
        int e = base + j * 256;
        if (m[j]) { t[j] = et[e]; s[j] = ei[e]; }
    }
    #pragma unroll
    for (int j = 0; j < 8; ++j)
        if (m[j]) rk[j] = atomicAdd(&cnt[(size_t)d[j] * RR + t[j]], 1);
    #pragma unroll
    for (int j = 0; j < 8; ++j) {
        int e = base + j * 256;
        if (m[j]) {
            rr[e] = (unsigned)rk[j] | ((unsigned)t[j] << 24);
            out_ei[e]     = (float)s[j];
            out_ei[E + e] = (float)d[j];
            out_et[e]     = (float)t[j];
        }
    }
}

// ---------------------------------------------------------------------------
// Per-dst bucket allocation (padded to x16 for the 16-deep gather) +
// per-(dst,rel) cell starts so scatter needs NO atomics. Pads (src=N ->
// zero row) written after run 7.
// ---------------------------------------------------------------------------
__global__ __launch_bounds__(256) void k_alloc(
    const int* __restrict__ cnt, int* __restrict__ startv,
    int* __restrict__ start2, int* __restrict__ counter,
    int* __restrict__ sorted, int N)
{
    __shared__ int sdata[256];
    __shared__ int sbase;
    const int tid = threadIdx.x;
    const int n = blockIdx.x * 256 + tid;

    int deg = 0, deg16 = 0;
    int c[RR];
    if (n < N) {
        const int4* c4 = (const int4*)(cnt + (size_t)n * RR);
        int4 a = c4[0], b = c4[1];
        c[0]=a.x; c[1]=a.y; c[2]=a.z; c[3]=a.w;
        c[4]=b.x; c[5]=b.y; c[6]=b.z; c[7]=b.w;
        #pragma unroll
        for (int r = 0; r < RR; ++r) deg += c[r];
        deg16 = (deg + 15) & ~15;
    }
    sdata[tid] = deg16;
    __syncthreads();
    int v = deg16;
    #pragma unroll
    for (int off = 1; off < 256; off <<= 1) {
        int t = (tid >= off) ? sdata[tid - off] : 0;
        __syncthreads();
        v += t;
        sdata[tid] = v;
        __syncthreads();
    }
    if (tid == 255) sbase = atomicAdd(counter, v);
    __syncthreads();
    if (n < N) {
        int st = sbase + v - deg16;
        startv[n] = st;
        int h = st;
        #pragma unroll
        for (int r = 0; r < RR; ++r) { start2[(size_t)n * RR + r] = h; h += c[r]; }
        for (int j = deg; j < deg16; ++j) sorted[st + j] = N;  // pad -> zero row
    }
}

// ---------------------------------------------------------------------------
// Partitioned scatter, NO atomics: pos = start2[cell] + rank (from rr).
// ---------------------------------------------------------------------------
__global__ __launch_bounds__(256) void k_scatter_part(
    const int* __restrict__ ei, const unsigned* __restrict__ rr,
    const int* __restrict__ start2, int* __restrict__ sorted, int E, int N)
{
    const int p    = blockIdx.x & (NPART - 1);
    const int sb   = blockIdx.x / NPART;
    const int dlo  = (int)((long long)N * p / NPART);
    const int dhi  = (int)((long long)N * (p + 1) / NPART);
    const int base = sb * ECH + threadIdx.x;

    int d[8]; bool m[8]; unsigned q[8]; int s[8], st[8];
    #pragma unroll
    for (int j = 0; j < 8; ++j) {
        int e = base + j * 256;
        d[j] = (e < E) ? ei[E + e] : -1;
    }
    #pragma unroll
    for (int j = 0; j < 8; ++j) m[j] = (d[j] >= dlo && d[j] < dhi);
    #pragma unroll
    for (int j = 0; j < 8; ++j) {
        int e = base + j * 256;
        if (m[j]) { q[j] = rr[e]; s[j] = ei[e]; }
    }
    #pragma unroll
    for (int j = 0; j < 8; ++j)
        if (m[j]) st[j] = start2[(size_t)d[j] * RR + (q[j] >> 24)];
    #pragma unroll
    for (int j = 0; j < 8; ++j)
        if (m[j]) sorted[st[j] + (q[j] & 0xFFFFFFu)] = s[j];
}

// ---------------------------------------------------------------------------
// Pack Wcat = [W_rel(8) ; W_root] into MFMA-B fragment order (bf16 hi only).
// ---------------------------------------------------------------------------
__global__ void k_packW(const float* __restrict__ Wrel, const float* __restrict__ Wroot,
                        unsigned short* __restrict__ Bh)
{
    int idx = blockIdx.x * 256 + threadIdx.x;
    if (idx >= NT * 4 * 64 * 8) return;
    int i    = idx & 7;
    int lane = (idx >> 3) & 63;
    int f    = (idx >> 9) & 3;
    int t    = idx >> 11;
    int k = t * 32 + (lane >> 4) * 8 + i;
    int d = f * 16 + (lane & 15);
    int r = k >> 6, kk = k & 63;
    float w = (r < RR) ? Wrel[((size_t)r * DD + kk) * DD + d]
                       : Wroot[(size_t)kk * DD + d];
    Bh[idx] = f2bf(w);
}

// ---------------------------------------------------------------------------
// FUSED aggregate + transform. Block = 512 threads (8 waves), 32 dsts.
// Phase 1: per-dst run-flush gather with 16-EDGE BATCHES — 16 readlanes +
//   16 independent xb loads issued before the first consume -> 2x the
//   outstanding misses of round 12/14. Buckets padded to x16 (pads hit the
//   L1-resident zero row). Setup (cnt, startv) hoisted per wave.
// Phase 2: 32x576 @ 576x64 MFMA; wave wv -> rows (wv&1)*16, col-frag wv>>1.
// LDS = 36.9KB -> 4 blocks/CU -> full occupancy.
// ---------------------------------------------------------------------------
__global__ __launch_bounds__(512) void k_agg_mfma(
    const unsigned short* __restrict__ xb, const int* __restrict__ sorted,
    const int* __restrict__ startv, const int* __restrict__ cnt,
    const unsigned short* __restrict__ Bh, const float* __restrict__ bias,
    float* __restrict__ out, int N)
{
    __shared__ __align__(16) unsigned short As[TILE * KA];   // 36864 B
    const int nb   = blockIdx.x * TILE;
    const int wv   = threadIdx.x >> 6;
    const int lane = threadIdx.x & 63;

    // ================= phase 1: aggregate 4 dsts per wave =================
    const int row0 = wv * 4;
    const int dst0 = nb + row0;
    const int nv   = min(4, N - dst0);
    if (nv > 0) {
        // hoisted setup: 32 cnt cells (lane i*8+r) + 4 startv entries
        int cidx = lane & 31;
        if (cidx >= nv * 8) cidx = nv * 8 - 1;          // clamp (safety)
        const int cv = cnt[(size_t)dst0 * RR + cidx];
        int sidx = lane & 3;
        if (sidx >= nv) sidx = nv - 1;
        const int sv = startv[dst0 + sidx];

        for (int i = 0; i < 4; ++i) {
            if (i >= nv) break;                         // wave-uniform
            const int row = row0 + i;
            const int dst = dst0 + i;
            const int xsh = (row & 7) << 3;             // XOR swizzle (shorts)
            unsigned short* ao = As + row * KA;
            const int cb = i * 8;                       // uniform cnt base

            int deg = 0;
            #pragma unroll
            for (int r = 0; r < RR; ++r)
                deg += __builtin_amdgcn_readlane(cv, cb + r);
            const int deg16 = (deg + 15) & ~15;

            const int s0  = __builtin_amdgcn_readlane(sv, i);
            const int end = s0 + deg16;

            int   r      = 0;
            int   c_r    = __builtin_amdgcn_readlane(cv, cb);
            int   next_b = s0 + c_r;
            float cur    = 0.f;

            auto flush = [&]() {
                float inv = __builtin_amdgcn_rcpf(fmaxf((float)c_r, 1.f));
                ao[(r * DD + lane) ^ xsh] = f2bf(cur * inv);
                cur = 0.f;
                ++r;
                c_r = __builtin_amdgcn_readlane(cv, cb + (r & 7));
                next_b += c_r;
            };

            int e = s0;
            int wbase = s0;
            int vidx  = sorted[wbase + lane];
            while (e < end) {
                if (e - wbase >= 64) {                 // slide index window
                    wbase = e;
                    vidx  = sorted[wbase + lane];
                }
                const int k    = e - wbase;            // uniform, mult of 16
                const int take = min(end - e, 64 - k); // mult of 16
                for (int ii = 0; ii < take; ii += 16) {
                    // 16 readlanes (SGPRs) then 16 independent loads in flight
                    int q0  = __builtin_amdgcn_readlane(vidx, k + ii + 0);
                    int q1  = __builtin_amdgcn_readlane(vidx, k + ii + 1);
                    int q2  = __builtin_amdgcn_readlane(vidx, k + ii + 2);
                    int q3  = __builtin_amdgcn_readlane(vidx, k + ii + 3);
                    int q4  = __builtin_amdgcn_readlane(vidx, k + ii + 4);
                    int q5  = __builtin_amdgcn_readlane(vidx, k + ii + 5);
                    int q6  = __builtin_amdgcn_readlane(vidx, k + ii + 6);
                    int q7  = __builtin_amdgcn_readlane(vidx, k + ii + 7);
                    int q8  = __builtin_amdgcn_readlane(vidx, k + ii + 8);
                    int q9  = __builtin_amdgcn_readlane(vidx, k + ii + 9);
                    int q10 = __builtin_amdgcn_readlane(vidx, k + ii + 10);
                    int q11 = __builtin_amdgcn_readlane(vidx, k + ii + 11);
                    int q12 = __builtin_amdgcn_readlane(vidx, k + ii + 12);
                    int q13 = __builtin_amdgcn_readlane(vidx, k + ii + 13);
                    int q14 = __builtin_amdgcn_readlane(vidx, k + ii + 14);
                    int q15 = __builtin_amdgcn_readlane(vidx, k + ii + 15);
                    unsigned short u0  = xb[(size_t)q0  * DD + lane];
                    unsigned short u1  = xb[(size_t)q1  * DD + lane];
                    unsigned short u2  = xb[(size_t)q2  * DD + lane];
                    unsigned short u3  = xb[(size_t)q3  * DD + lane];
                    unsigned short u4  = xb[(size_t)q4  * DD + lane];
                    unsigned short u5  = xb[(size_t)q5  * DD + lane];
                    unsigned short u6  = xb[(size_t)q6  * DD + lane];
                    unsigned short u7  = xb[(size_t)q7  * DD + lane];
                    unsigned short u8  = xb[(size_t)q8  * DD + lane];
                    unsigned short u9  = xb[(size_t)q9  * DD + lane];
                    unsigned short u10 = xb[(size_t)q10 * DD + lane];
                    unsigned short u11 = xb[(size_t)q11 * DD + lane];
                    unsigned short u12 = xb[(size_t)q12 * DD + lane];
                    unsigned short u13 = xb[(size_t)q13 * DD + lane];
                    unsigned short u14 = xb[(size_t)q14 * DD + lane];
                    unsigned short u15 = xb[(size_t)q15 * DD + lane];
                    const int base = e + ii;
                    while (base + 0  == next_b && r < RR) flush();
                    cur += bf2f(u0);
                    while (base + 1  == next_b && r < RR) flush();
                    cur += bf2f(u1);
                    while (base + 2  == next_b && r < RR) flush();
                    cur += bf2f(u2);
                    while (base + 3  == next_b && r < RR) flush();
                    cur += bf2f(u3);
                    while (base + 4  == next_b && r < RR) flush();
                    cur += bf2f(u4);
                    while (base + 5  == next_b && r < RR) flush();
                    cur += bf2f(u5);
                    while (base + 6  == next_b && r < RR) flush();
                    cur += bf2f(u6);
                    while (base + 7  == next_b && r < RR) flush();
                    cur += bf2f(u7);
                    while (base + 8  == next_b && r < RR) flush();
                    cur += bf2f(u8);
                    while (base + 9  == next_b && r < RR) flush();
                    cur += bf2f(u9);
                    while (base + 10 == next_b && r < RR) flush();
                    cur += bf2f(u10);
                    while (base + 11 == next_b && r < RR) flush();
                    cur += bf2f(u11);
                    while (base + 12 == next_b && r < RR) flush();
                    cur += bf2f(u12);
                    while (base + 13 == next_b && r < RR) flush();
                    cur += bf2f(u13);
                    while (base + 14 == next_b && r < RR) flush();
                    cur += bf2f(u14);
                    while (base + 15 == next_b && r < RR) flush();
                    cur += bf2f(u15);
                }
                e += take;
            }
            while (r < RR) flush();                    // drain (covers empties)

            ao[(8 * DD + lane) ^ xsh] = xb[(size_t)dst * DD + lane];  // x row
        }
    }

    __syncthreads();

    // ================= phase 2: MFMA from LDS A =================
    const int rlo = lane & 15;
    const int kg  = lane >> 4;
    const int rg  = (wv & 1) * 16;                 // row group (2 x 16 = 32)
    const int cf  = wv >> 1;                       // col frag (4 x 16 = 64)
    const int row = rg + rlo;
    const int xsh = (row & 7) << 3;

    f32x4 acc = {0.f,0.f,0.f,0.f};

    const unsigned short* arow = As + row * KA;
    #pragma unroll
    for (int t = 0; t < NT; ++t) {
        bf16x8 a = *(const bf16x8*)(arow + ((t * 32 + kg * 8) ^ xsh));
        bf16x8 b = *(const bf16x8*)(Bh + (size_t)t * 2048 + (size_t)cf * 512
                                       + lane * 8);
        acc = __builtin_amdgcn_mfma_f32_16x16x32_bf16(a, b, acc, 0, 0, 0);
    }

    // C/D layout: col = lane&15, row = (lane>>4)*4 + reg
    const float bl = bias[rlo + cf * 16];
    const int orow = nb + rg + kg * 4;
    #pragma unroll
    for (int j = 0; j < 4; ++j) {
        int rr2 = orow + j;
        if (rr2 < N) out[(size_t)rr2 * DD + rlo + cf * 16] = acc[j] + bl;
    }
}

extern "C" void kernel_launch(void* const* d_in, const int* in_sizes, int n_in,
                              void* d_out, int out_size, void* d_ws, size_t ws_size,
                              hipStream_t stream)
{
    const float* x     = (const float*)d_in[0];
    const int*   ei    = (const int*)d_in[1];
    const int*   et    = (const int*)d_in[2];
    const float* Wrel  = (const float*)d_in[3];
    const float* Wroot = (const float*)d_in[4];
    const float* bias  = (const float*)d_in[5];

    const int N = in_sizes[0] / DD;
    const int E = in_sizes[2];
    const int M = N * RR;

    float* out    = (float*)d_out;
    float* out_ei = out + (size_t)N * DD;
    float* out_et = out_ei + (size_t)2 * E;

    auto align = [](size_t v) { return (v + 255) & ~(size_t)255; };

    // workspace layout
    size_t p = 0;
    int* cnt = (int*)((char*)d_ws + p);              p += align((size_t)M * 4);
    int* counter = (int*)((char*)d_ws + p);
    size_t zero_bytes = p + 256;                     p += 256;
    int* startv = (int*)((char*)d_ws + p);           p += align((size_t)N * 4);
    int* start2 = (int*)((char*)d_ws + p);           p += align((size_t)M * 4);
    unsigned* rr = (unsigned*)((char*)d_ws + p);     p += align((size_t)E * 4);
    int* sorted = (int*)((char*)d_ws + p);           p += align(((size_t)E + 15*(size_t)N + 256) * 4);
    unsigned short* xb = (unsigned short*)((char*)d_ws + p); p += align(((size_t)N + 1) * DD * 2);
    unsigned short* Bh = (unsigned short*)((char*)d_ws + p); p += align((size_t)NT*4*64*8*2);

    hipMemsetAsync(d_ws, 0, zero_bytes, stream);     // cnt + counter

    const int nsb = (E + ECH - 1) / ECH;             // slice-blocks per partition

    k_xcast <<<dim3(((N + 1) * (DD/4) + 255) / 256), 256, 0, stream>>>(x, xb, N);
    k_packW <<<dim3((NT*4*64*8 + 255) / 256), 256, 0, stream>>>(Wrel, Wroot, Bh);
    k_count_rank_echo <<<dim3(nsb), 256, 0, stream>>>(ei, et, cnt, rr,
                                                      out_ei, out_et, E);
    k_alloc <<<dim3((N + 255) / 256), 256, 0, stream>>>(cnt, startv, start2,
                                                        counter, sorted, N);
    k_scatter_part<<<dim3(nsb * NPART), 256, 0, stream>>>(ei, rr, start2, sorted, E, N);

    k_agg_mfma<<<dim3((N + TILE - 1) / TILE), 512, 0, stream>>>(
        xb, sorted, startv, cnt, Bh, bias, out, N);
}

// Round 16
// 212.390 us; speedup vs baseline: 1.0507x; 1.0507x over previous
//
#include <hip/hip_runtime.h>

#define DD 64          // node embedding dim
#define RR 8           // num relations
#define KA 576         // (RR+1)*DD : agg rows 0..7 + x as "relation 8"
#define NT 18          // K steps = KA/32
#define NPART 8        // dst partitions ~ XCDs (blockIdx%8 round-robin)
#define ECH 2048       // edges per slice-block in partitioned kernels
#define TILE 16        // dsts per fused block (18.4KB LDS -> 8 blocks/CU)

typedef short bf16x8 __attribute__((ext_vector_type(8)));   // 8 bf16
typedef float f32x4  __attribute__((ext_vector_type(4)));

__device__ __forceinline__ float bf2f(unsigned short u) {
    union { unsigned u; float f; } c; c.u = ((unsigned)u) << 16; return c.f;
}
__device__ __forceinline__ unsigned short f2bf(float f) {
    union { float f; unsigned u; } c; c.f = f;
    unsigned u = c.u;
    u += 0x7FFF + ((u >> 16) & 1);      // round-to-nearest-even
    return (unsigned short)(u >> 16);
}

// ---------------------------------------------------------------------------
// x -> bf16 rows; row N is an all-zero pad row (targets of dummy pad edges).
// ---------------------------------------------------------------------------
__global__ void k_xcast(const float* __restrict__ x, unsigned short* __restrict__ xb,
                        int N)
{
    int i = blockIdx.x * 256 + threadIdx.x;              // quad index
    int total = (N + 1) * (DD / 4);
    if (i >= total) return;
    ushort4 o;
    if (i < N * (DD / 4)) {
        float4 f = ((const float4*)x)[i];
        o = make_ushort4(f2bf(f.x), f2bf(f.y), f2bf(f.z), f2bf(f.w));
    } else {
        o = make_ushort4(0, 0, 0, 0);
    }
    ((ushort4*)xb)[i] = o;
}

// ---------------------------------------------------------------------------
// Count + rank + edge echo fused (full-lane, 8-deep): 8 independent returning
// atomics in flight per thread. rr = rank | rel<<24. Echo of edge_index /
// edge_type piggybacks on the loads already needed here.
// ---------------------------------------------------------------------------
__global__ __launch_bounds__(256) void k_count_rank_echo(
    const int* __restrict__ ei, const int* __restrict__ et,
    int* __restrict__ cnt, unsigned* __restrict__ rr,
    float* __restrict__ out_ei, float* __restrict__ out_et, int E)
{
    const int base = blockIdx.x * ECH + threadIdx.x;
    int d[8], t[8], s[8], rk[8]; bool m[8];
    #pragma unroll
    for (int j = 0; j < 8; ++j) {
        int e = base + j * 256;
        m[j] = (e < E);
        d[j] = m[j] ? ei[E + e] : 0;
    }
    #pragma unroll
    for (int j = 0; j < 8; ++j) {
        int e = base + j * 256;
        if (m[j]) { t[j] = et[e]; s[j] = ei[e]; }
    }
    #pragma unroll
    for (int j = 0; j < 8; ++j)
        if (m[j]) rk[j] = atomicAdd(&cnt[(size_t)d[j] * RR + t[j]], 1);
    #pragma unroll
    for (int j = 0; j < 8; ++j) {
        int e = base + j * 256;
        if (m[j]) {
            rr[e] = (unsigned)rk[j] | ((unsigned)t[j] << 24);
            out_ei[e]     = (float)s[j];
            out_ei[E + e] = (float)d[j];
            out_et[e]     = (float)t[j];
        }
    }
}

// ---------------------------------------------------------------------------
// Per-dst bucket allocation (padded to x8) + per-(dst,rel) cell starts, so
// scatter can compute positions WITHOUT atomics. Pads (src=N -> zero row)
// written after run 7. In-block scan keeps consecutive dsts contiguous.
// ---------------------------------------------------------------------------
__global__ __launch_bounds__(256) void k_alloc(
    const int* __restrict__ cnt, int* __restrict__ startv,
    int* __restrict__ start2, int* __restrict__ counter,
    int* __restrict__ sorted, int N)
{
    __shared__ int sdata[256];
    __shared__ int sbase;
    const int tid = threadIdx.x;
    const int n = blockIdx.x * 256 + tid;

    int deg = 0, deg8 = 0;
    int c[RR];
    if (n < N) {
        const int4* c4 = (const int4*)(cnt + (size_t)n * RR);
        int4 a = c4[0], b = c4[1];
        c[0]=a.x; c[1]=a.y; c[2]=a.z; c[3]=a.w;
        c[4]=b.x; c[5]=b.y; c[6]=b.z; c[7]=b.w;
        #pragma unroll
        for (int r = 0; r < RR; ++r) deg += c[r];
        deg8 = (deg + 7) & ~7;
    }
    sdata[tid] = deg8;
    __syncthreads();
    int v = deg8;
    #pragma unroll
    for (int off = 1; off < 256; off <<= 1) {
        int t = (tid >= off) ? sdata[tid - off] : 0;
        __syncthreads();
        v += t;
        sdata[tid] = v;
        __syncthreads();
    }
    if (tid == 255) sbase = atomicAdd(counter, v);
    __syncthreads();
    if (n < N) {
        int st = sbase + v - deg8;
        startv[n] = st;
        int h = st;
        #pragma unroll
        for (int r = 0; r < RR; ++r) { start2[(size_t)n * RR + r] = h; h += c[r]; }
        for (int j = deg; j < deg8; ++j) sorted[st + j] = N;   // pad -> zero row
    }
}

// ---------------------------------------------------------------------------
// Partitioned scatter, NO atomics: pos = start2[cell] + rank (from rr).
// ---------------------------------------------------------------------------
__global__ __launch_bounds__(256) void k_scatter_part(
    const int* __restrict__ ei, const unsigned* __restrict__ rr,
    const int* __restrict__ start2, int* __restrict__ sorted, int E, int N)
{
    const int p    = blockIdx.x & (NPART - 1);
    const int sb   = blockIdx.x / NPART;
    const int dlo  = (int)((long long)N * p / NPART);
    const int dhi  = (int)((long long)N * (p + 1) / NPART);
    const int base = sb * ECH + threadIdx.x;

    int d[8]; bool m[8]; unsigned q[8]; int s[8], st[8];
    #pragma unroll
    for (int j = 0; j < 8; ++j) {
        int e = base + j * 256;
        d[j] = (e < E) ? ei[E + e] : -1;
    }
    #pragma unroll
    for (int j = 0; j < 8; ++j) m[j] = (d[j] >= dlo && d[j] < dhi);
    #pragma unroll
    for (int j = 0; j < 8; ++j) {
        int e = base + j * 256;
        if (m[j]) { q[j] = rr[e]; s[j] = ei[e]; }
    }
    #pragma unroll
    for (int j = 0; j < 8; ++j)
        if (m[j]) st[j] = start2[(size_t)d[j] * RR + (q[j] >> 24)];
    #pragma unroll
    for (int j = 0; j < 8; ++j)
        if (m[j]) sorted[st[j] + (q[j] & 0xFFFFFFu)] = s[j];
}

// ---------------------------------------------------------------------------
// Pack Wcat = [W_rel(8) ; W_root] into MFMA-B fragment order (bf16 hi only).
// ---------------------------------------------------------------------------
__global__ void k_packW(const float* __restrict__ Wrel, const float* __restrict__ Wroot,
                        unsigned short* __restrict__ Bh)
{
    int idx = blockIdx.x * 256 + threadIdx.x;
    if (idx >= NT * 4 * 64 * 8) return;
    int i    = idx & 7;
    int lane = (idx >> 3) & 63;
    int f    = (idx >> 9) & 3;
    int t    = idx >> 11;
    int k = t * 32 + (lane >> 4) * 8 + i;
    int d = f * 16 + (lane & 15);
    int r = k >> 6, kk = k & 63;
    float w = (r < RR) ? Wrel[((size_t)r * DD + kk) * DD + d]
                       : Wroot[(size_t)kk * DD + d];
    Bh[idx] = f2bf(w);
}

// ---------------------------------------------------------------------------
// FUSED aggregate + transform. Block = 256 threads (4 waves), 16 dsts.
// Smaller block than r12: barrier couples only 4 waves (16 dsts) -> less
// degree-imbalance loss; LDS 18.4KB -> 8 blocks/CU -> 32 waves/CU (max).
// Phase 1: wave wv aggregates dsts [wv*4, wv*4+4) with the r14 run-flush
//   gather (8-deep batches, deg8 padding), setup loads hoisted per wave.
// Phase 2: 16x576 @ 576x64 MFMA; wave wv -> col-frag wv (rows shared).
// ---------------------------------------------------------------------------
__global__ __launch_bounds__(256) void k_agg_mfma(
    const unsigned short* __restrict__ xb, const int* __restrict__ sorted,
    const int* __restrict__ startv, const int* __restrict__ cnt,
    const unsigned short* __restrict__ Bh, const float* __restrict__ bias,
    float* __restrict__ out, int N)
{
    __shared__ __align__(16) unsigned short As[TILE * KA];   // 18432 B
    const int nb   = blockIdx.x * TILE;
    const int wv   = threadIdx.x >> 6;
    const int lane = threadIdx.x & 63;

    // ================= phase 1: aggregate 4 dsts per wave =================
    const int row0 = wv * 4;
    const int dst0 = nb + row0;
    const int nv   = min(4, N - dst0);
    if (nv > 0) {
        // hoisted setup: 32 cnt cells (lane i*8+r) + 4 startv entries
        int cidx = lane & 31;
        if (cidx >= nv * 8) cidx = nv * 8 - 1;          // clamp (safety)
        const int cv = cnt[(size_t)dst0 * RR + cidx];
        int sidx = lane & 3;
        if (sidx >= nv) sidx = nv - 1;
        const int sv = startv[dst0 + sidx];

        for (int i = 0; i < 4; ++i) {
            if (i >= nv) break;                         // wave-uniform
            const int row = row0 + i;
            const int dst = dst0 + i;
            const int xsh = (row & 7) << 3;             // XOR swizzle (shorts)
            unsigned short* ao = As + row * KA;
            const int cb = i * 8;                       // uniform cnt base

            int deg = 0;
            #pragma unroll
            for (int r = 0; r < RR; ++r)
                deg += __builtin_amdgcn_readlane(cv, cb + r);
            const int deg8 = (deg + 7) & ~7;

            const int s0  = __builtin_amdgcn_readlane(sv, i);
            const int end = s0 + deg8;

            int   r      = 0;
            int   c_r    = __builtin_amdgcn_readlane(cv, cb);
            int   next_b = s0 + c_r;
            float cur    = 0.f;

            auto flush = [&]() {
                float inv = __builtin_amdgcn_rcpf(fmaxf((float)c_r, 1.f));
                ao[(r * DD + lane) ^ xsh] = f2bf(cur * inv);
                cur = 0.f;
                ++r;
                c_r = __builtin_amdgcn_readlane(cv, cb + (r & 7));
                next_b += c_r;
            };

            int e = s0;
            int wbase = s0;
            int vidx  = sorted[wbase + lane];
            while (e < end) {
                if (e - wbase >= 64) {                 // slide index window
                    wbase = e;
                    vidx  = sorted[wbase + lane];
                }
                const int k    = e - wbase;            // uniform, multiple of 8
                const int take = min(end - e, 64 - k); // multiple of 8
                for (int ii = 0; ii < take; ii += 8) {
                    int q0 = __builtin_amdgcn_readlane(vidx, k + ii + 0);
                    int q1 = __builtin_amdgcn_readlane(vidx, k + ii + 1);
                    int q2 = __builtin_amdgcn_readlane(vidx, k + ii + 2);
                    int q3 = __builtin_amdgcn_readlane(vidx, k + ii + 3);
                    int q4 = __builtin_amdgcn_readlane(vidx, k + ii + 4);
                    int q5 = __builtin_amdgcn_readlane(vidx, k + ii + 5);
                    int q6 = __builtin_amdgcn_readlane(vidx, k + ii + 6);
                    int q7 = __builtin_amdgcn_readlane(vidx, k + ii + 7);
                    unsigned short u0 = xb[(size_t)q0 * DD + lane];  // 8 in flight
                    unsigned short u1 = xb[(size_t)q1 * DD + lane];
                    unsigned short u2 = xb[(size_t)q2 * DD + lane];
                    unsigned short u3 = xb[(size_t)q3 * DD + lane];
                    unsigned short u4 = xb[(size_t)q4 * DD + lane];
                    unsigned short u5 = xb[(size_t)q5 * DD + lane];
                    unsigned short u6 = xb[(size_t)q6 * DD + lane];
                    unsigned short u7 = xb[(size_t)q7 * DD + lane];
                    const int base = e + ii;
                    while (base + 0 == next_b && r < RR) flush();
                    cur += bf2f(u0);
                    while (base + 1 == next_b && r < RR) flush();
                    cur += bf2f(u1);
                    while (base + 2 == next_b && r < RR) flush();
                    cur += bf2f(u2);
                    while (base + 3 == next_b && r < RR) flush();
                    cur += bf2f(u3);
                    while (base + 4 == next_b && r < RR) flush();
                    cur += bf2f(u4);
                    while (base + 5 == next_b && r < RR) flush();
                    cur += bf2f(u5);
                    while (base + 6 == next_b && r < RR) flush();
                    cur += bf2f(u6);
                    while (base + 7 == next_b && r < RR) flush();
                    cur += bf2f(u7);
                }
                e += take;
            }
            while (r < RR) flush();                    // drain (covers empties)

            ao[(8 * DD + lane) ^ xsh] = xb[(size_t)dst * DD + lane];  // x row
        }
    }

    __syncthreads();

    // ================= phase 2: MFMA from LDS A =================
    const int rlo = lane & 15;
    const int kg  = lane >> 4;
    const int cf  = wv;                            // 4 col frags (4x16 = 64)
    const int row = rlo;                           // single 16-row group
    const int xsh = (row & 7) << 3;

    f32x4 acc = {0.f,0.f,0.f,0.f};

    const unsigned short* arow = As + row * KA;
    #pragma unroll
    for (int t = 0; t < NT; ++t) {
        bf16x8 a = *(const bf16x8*)(arow + ((t * 32 + kg * 8) ^ xsh));
        bf16x8 b = *(const bf16x8*)(Bh + (size_t)t * 2048 + (size_t)cf * 512
                                       + lane * 8);
        acc = __builtin_amdgcn_mfma_f32_16x16x32_bf16(a, b, acc, 0, 0, 0);
    }

    // C/D layout: col = lane&15, row = (lane>>4)*4 + reg
    const float bl = bias[rlo + cf * 16];
    const int orow = nb + kg * 4;
    #pragma unroll
    for (int j = 0; j < 4; ++j) {
        int rr2 = orow + j;
        if (rr2 < N) out[(size_t)rr2 * DD + rlo + cf * 16] = acc[j] + bl;
    }
}

extern "C" void kernel_launch(void* const* d_in, const int* in_sizes, int n_in,
                              void* d_out, int out_size, void* d_ws, size_t ws_size,
                              hipStream_t stream)
{
    const float* x     = (const float*)d_in[0];
    const int*   ei    = (const int*)d_in[1];
    const int*   et    = (const int*)d_in[2];
    const float* Wrel  = (const float*)d_in[3];
    const float* Wroot = (const float*)d_in[4];
    const float* bias  = (const float*)d_in[5];

    const int N = in_sizes[0] / DD;
    const int E = in_sizes[2];
    const int M = N * RR;

    float* out    = (float*)d_out;
    float* out_ei = out + (size_t)N * DD;
    float* out_et = out_ei + (size_t)2 * E;

    auto align = [](size_t v) { return (v + 255) & ~(size_t)255; };

    // workspace layout
    size_t p = 0;
    int* cnt = (int*)((char*)d_ws + p);              p += align((size_t)M * 4);
    int* counter = (int*)((char*)d_ws + p);
    size_t zero_bytes = p + 256;                     p += 256;
    int* startv = (int*)((char*)d_ws + p);           p += align((size_t)N * 4);
    int* start2 = (int*)((char*)d_ws + p);           p += align((size_t)M * 4);
    unsigned* rr = (unsigned*)((char*)d_ws + p);     p += align((size_t)E * 4);
    int* sorted = (int*)((char*)d_ws + p);           p += align(((size_t)E + 7*(size_t)N + 128) * 4);
    unsigned short* xb = (unsigned short*)((char*)d_ws + p); p += align(((size_t)N + 1) * DD * 2);
    unsigned short* Bh = (unsigned short*)((char*)d_ws + p); p += align((size_t)NT*4*64*8*2);

    hipMemsetAsync(d_ws, 0, zero_bytes, stream);     // cnt + counter

    const int nsb = (E + ECH - 1) / ECH;             // slice-blocks per partition

    k_xcast <<<dim3(((N + 1) * (DD/4) + 255) / 256), 256, 0, stream>>>(x, xb, N);
    k_packW <<<dim3((NT*4*64*8 + 255) / 256), 256, 0, stream>>>(Wrel, Wroot, Bh);
    k_count_rank_echo <<<dim3(nsb), 256, 0, stream>>>(ei, et, cnt, rr,
                                                      out_ei, out_et, E);
    k_alloc <<<dim3((N + 255) / 256), 256, 0, stream>>>(cnt, startv, start2,
                                                        counter, sorted, N);
    k_scatter_part<<<dim3(nsb * NPART), 256, 0, stream>>>(ei, rr, start2, sorted, E, N);

    k_agg_mfma<<<dim3((N + TILE - 1) / TILE), 256, 0, stream>>>(
        xb, sorted, startv, cnt, Bh, bias, out, N);
}

// Round 17
// 193.224 us; speedup vs baseline: 1.1549x; 1.0992x over previous
//
#include <hip/hip_runtime.h>

#define DD 64          // node embedding dim
#define RR 8           // num relations
#define KA 576         // (RR+1)*DD : agg rows 0..7 + x as "relation 8"
#define NT 18          // K steps = KA/32
#define NPART 8        // dst partitions ~ XCDs (blockIdx%8 round-robin)
#define ECH 2048       // edges per block in count kernel
#define TILE 16        // dsts per fused block (18.4KB LDS -> 8 blocks/CU)
#define SEGCAP 160     // per-(wave,partition) segment capacity (mean 64, 12sigma)

typedef short bf16x8 __attribute__((ext_vector_type(8)));   // 8 bf16
typedef float f32x4  __attribute__((ext_vector_type(4)));

__device__ __forceinline__ float bf2f(unsigned short u) {
    union { unsigned u; float f; } c; c.u = ((unsigned)u) << 16; return c.f;
}
__device__ __forceinline__ unsigned short f2bf(float f) {
    union { float f; unsigned u; } c; c.f = f;
    unsigned u = c.u;
    u += 0x7FFF + ((u >> 16) & 1);      // round-to-nearest-even
    return (unsigned short)(u >> 16);
}

// ---------------------------------------------------------------------------
// Fused prep: [0, xblocks) -> x->bf16 cast (+ zero pad row N);
//             [xblocks, ...) -> pack Wcat into MFMA-B fragment order.
// ---------------------------------------------------------------------------
__global__ __launch_bounds__(256) void k_prep(
    const float* __restrict__ x, unsigned short* __restrict__ xb,
    const float* __restrict__ Wrel, const float* __restrict__ Wroot,
    unsigned short* __restrict__ Bh, int N, int xblocks)
{
    if ((int)blockIdx.x < xblocks) {
        int i = blockIdx.x * 256 + threadIdx.x;              // quad index
        int total = (N + 1) * (DD / 4);
        if (i >= total) return;
        ushort4 o;
        if (i < N * (DD / 4)) {
            float4 f = ((const float4*)x)[i];
            o = make_ushort4(f2bf(f.x), f2bf(f.y), f2bf(f.z), f2bf(f.w));
        } else {
            o = make_ushort4(0, 0, 0, 0);
        }
        ((ushort4*)xb)[i] = o;
    } else {
        int idx = (blockIdx.x - xblocks) * 256 + threadIdx.x;
        if (idx >= NT * 4 * 64 * 8) return;
        int i    = idx & 7;
        int lane = (idx >> 3) & 63;
        int f    = (idx >> 9) & 3;
        int t    = idx >> 11;
        int k = t * 32 + (lane >> 4) * 8 + i;
        int d = f * 16 + (lane & 15);
        int r = k >> 6, kk = k & 63;
        float w = (r < RR) ? Wrel[((size_t)r * DD + kk) * DD + d]
                           : Wroot[(size_t)kk * DD + d];
        Bh[idx] = f2bf(w);
    }
}

// ---------------------------------------------------------------------------
// Count + rank + echo + WAVE-LOCAL COMPACTION (no extra atomics).
// Per edge: rank = atomicAdd(cnt[dst*8+rel]) (the only atomic). Each wave
// then routes its 512 edge-records (src|rel<<20, dst|rank<<20) into 8
// per-(wave,partition) segments via ballot prefix + register-resident
// running counters. Segment lines have a single writer wave -> no ping-pong.
// ---------------------------------------------------------------------------
__global__ __launch_bounds__(256) void k_count_rank_echo(
    const int* __restrict__ ei, const int* __restrict__ et,
    int* __restrict__ cnt, unsigned long long* __restrict__ q,
    int* __restrict__ qlen, float* __restrict__ out_ei,
    float* __restrict__ out_et, int E, unsigned pmagic)
{
    const int base = blockIdx.x * ECH + threadIdx.x;
    const int lane = threadIdx.x & 63;
    const int gwid = blockIdx.x * 4 + (threadIdx.x >> 6);

    int d[8], t[8], s[8], rk[8]; bool m[8];
    #pragma unroll
    for (int j = 0; j < 8; ++j) {
        int e = base + j * 256;
        m[j] = (e < E);
        d[j] = m[j] ? ei[E + e] : 0;
    }
    #pragma unroll
    for (int j = 0; j < 8; ++j) {
        int e = base + j * 256;
        if (m[j]) { t[j] = et[e]; s[j] = ei[e]; }
    }
    #pragma unroll
    for (int j = 0; j < 8; ++j)
        if (m[j]) rk[j] = atomicAdd(&cnt[(size_t)d[j] * RR + t[j]], 1);
    #pragma unroll
    for (int j = 0; j < 8; ++j) {
        int e = base + j * 256;
        if (m[j]) {
            out_ei[e]     = (float)s[j];
            out_ei[E + e] = (float)d[j];
            out_et[e]     = (float)t[j];
        }
    }

    // ---- compaction: partition tag p = mul_hi(dst, pmagic) in [0,7] ----
    int run0=0,run1=0,run2=0,run3=0,run4=0,run5=0,run6=0,run7=0;
    unsigned long long* qw = q + (size_t)gwid * NPART * SEGCAP;
    #pragma unroll
    for (int j = 0; j < 8; ++j) {
        int pj = m[j]
            ? (int)(((unsigned long long)(unsigned)d[j] * pmagic) >> 32)
            : -1;
        unsigned long long k0 = __ballot(pj == 0);
        unsigned long long k1 = __ballot(pj == 1);
        unsigned long long k2 = __ballot(pj == 2);
        unsigned long long k3 = __ballot(pj == 3);
        unsigned long long k4 = __ballot(pj == 4);
        unsigned long long k5 = __ballot(pj == 5);
        unsigned long long k6 = __ballot(pj == 6);
        unsigned long long k7 = __ballot(pj == 7);
        unsigned long long km =
            (pj==0)?k0:(pj==1)?k1:(pj==2)?k2:(pj==3)?k3:
            (pj==4)?k4:(pj==5)?k5:(pj==6)?k6:k7;
        int bb =
            (pj==0)?run0:(pj==1)?run1:(pj==2)?run2:(pj==3)?run3:
            (pj==4)?run4:(pj==5)?run5:(pj==6)?run6:run7;
        int off = __popcll(km & ((1ull << lane) - 1ull));
        if (pj >= 0 && bb + off < SEGCAP) {
            unsigned lo = (unsigned)s[j] | ((unsigned)t[j]  << 20);
            unsigned hi = (unsigned)d[j] | ((unsigned)rk[j] << 20);
            qw[(size_t)pj * SEGCAP + bb + off] =
                ((unsigned long long)hi << 32) | lo;
        }
        run0 += __popcll(k0); run1 += __popcll(k1);
        run2 += __popcll(k2); run3 += __popcll(k3);
        run4 += __popcll(k4); run5 += __popcll(k5);
        run6 += __popcll(k6); run7 += __popcll(k7);
    }
    if (lane == 0) {
        int* ql = qlen + (size_t)gwid * NPART;
        ql[0]=run0; ql[1]=run1; ql[2]=run2; ql[3]=run3;
        ql[4]=run4; ql[5]=run5; ql[6]=run6; ql[7]=run7;
    }
}

// ---------------------------------------------------------------------------
// Per-dst bucket allocation (padded to x8) + per-(dst,rel) cell starts, so
// scatter can compute positions WITHOUT atomics. Pads (src=N -> zero row)
// written after run 7.
// ---------------------------------------------------------------------------
__global__ __launch_bounds__(256) void k_alloc(
    const int* __restrict__ cnt, int* __restrict__ startv,
    int* __restrict__ start2, int* __restrict__ counter,
    int* __restrict__ sorted, int N)
{
    __shared__ int sdata[256];
    __shared__ int sbase;
    const int tid = threadIdx.x;
    const int n = blockIdx.x * 256 + tid;

    int deg = 0, deg8 = 0;
    int c[RR];
    if (n < N) {
        const int4* c4 = (const int4*)(cnt + (size_t)n * RR);
        int4 a = c4[0], b = c4[1];
        c[0]=a.x; c[1]=a.y; c[2]=a.z; c[3]=a.w;
        c[4]=b.x; c[5]=b.y; c[6]=b.z; c[7]=b.w;
        #pragma unroll
        for (int r = 0; r < RR; ++r) deg += c[r];
        deg8 = (deg + 7) & ~7;
    }
    sdata[tid] = deg8;
    __syncthreads();
    int v = deg8;
    #pragma unroll
    for (int off = 1; off < 256; off <<= 1) {
        int t = (tid >= off) ? sdata[tid - off] : 0;
        __syncthreads();
        v += t;
        sdata[tid] = v;
        __syncthreads();
    }
    if (tid == 255) sbase = atomicAdd(counter, v);
    __syncthreads();
    if (n < N) {
        int st = sbase + v - deg8;
        startv[n] = st;
        int h = st;
        #pragma unroll
        for (int r = 0; r < RR; ++r) { start2[(size_t)n * RR + r] = h; h += c[r]; }
        for (int j = deg; j < deg8; ++j) sorted[st + j] = N;   // pad -> zero row
    }
}

// ---------------------------------------------------------------------------
// Segment scatter: one wave per (wave,partition) segment, read-once.
// Block b = grp*8+p handles partition p only -> stores stay XCD-local.
// pos = start2[dst*8+rel] + rank; sorted[pos] = src. No atomics, no rescans.
// ---------------------------------------------------------------------------
__global__ __launch_bounds__(256) void k_scatter_seg(
    const unsigned long long* __restrict__ q, const int* __restrict__ qlen,
    const int* __restrict__ start2, int* __restrict__ sorted, int nwaves)
{
    const int p    = blockIdx.x & (NPART - 1);
    const int grp  = blockIdx.x / NPART;
    const int gwid = grp * 4 + (threadIdx.x >> 6);
    const int lane = threadIdx.x & 63;
    if (gwid >= nwaves) return;
    const int seg = gwid * NPART + p;
    const int len = qlen[seg];
    const unsigned long long* qs = q + (size_t)seg * SEGCAP;
    for (int i = lane; i < len; i += 64) {
        unsigned long long v = qs[i];
        int cell = (int)((v >> 32) & 0xFFFFFu) * RR + (int)((v >> 20) & 7u);
        int pos  = start2[cell] + (int)(v >> 52);
        sorted[pos] = (int)(v & 0xFFFFFu);
    }
}

// ---------------------------------------------------------------------------
// FUSED aggregate + transform (unchanged from round 16: 80us, best).
// Block = 256 threads (4 waves), 16 dsts; LDS 18.4KB -> 8 blocks/CU.
// ---------------------------------------------------------------------------
__global__ __launch_bounds__(256) void k_agg_mfma(
    const unsigned short* __restrict__ xb, const int* __restrict__ sorted,
    const int* __restrict__ startv, const int* __restrict__ cnt,
    const unsigned short* __restrict__ Bh, const float* __restrict__ bias,
    float* __restrict__ out, int N)
{
    __shared__ __align__(16) unsigned short As[TILE * KA];   // 18432 B
    const int nb   = blockIdx.x * TILE;
    const int wv   = threadIdx.x >> 6;
    const int lane = threadIdx.x & 63;

    // ================= phase 1: aggregate 4 dsts per wave =================
    const int row0 = wv * 4;
    const int dst0 = nb + row0;
    const int nv   = min(4, N - dst0);
    if (nv > 0) {
        int cidx = lane & 31;
        if (cidx >= nv * 8) cidx = nv * 8 - 1;          // clamp (safety)
        const int cv = cnt[(size_t)dst0 * RR + cidx];
        int sidx = lane & 3;
        if (sidx >= nv) sidx = nv - 1;
        const int sv = startv[dst0 + sidx];

        for (int i = 0; i < 4; ++i) {
            if (i >= nv) break;                         // wave-uniform
            const int row = row0 + i;
            const int dst = dst0 + i;
            const int xsh = (row & 7) << 3;             // XOR swizzle (shorts)
            unsigned short* ao = As + row * KA;
            const int cb = i * 8;                       // uniform cnt base

            int deg = 0;
            #pragma unroll
            for (int r = 0; r < RR; ++r)
                deg += __builtin_amdgcn_readlane(cv, cb + r);
            const int deg8 = (deg + 7) & ~7;

            const int s0  = __builtin_amdgcn_readlane(sv, i);
            const int end = s0 + deg8;

            int   r      = 0;
            int   c_r    = __builtin_amdgcn_readlane(cv, cb);
            int   next_b = s0 + c_r;
            float cur    = 0.f;

            auto flush = [&]() {
                float inv = __builtin_amdgcn_rcpf(fmaxf((float)c_r, 1.f));
                ao[(r * DD + lane) ^ xsh] = f2bf(cur * inv);
                cur = 0.f;
                ++r;
                c_r = __builtin_amdgcn_readlane(cv, cb + (r & 7));
                next_b += c_r;
            };

            int e = s0;
            int wbase = s0;
            int vidx  = sorted[wbase + lane];
            while (e < end) {
                if (e - wbase >= 64) {                 // slide index window
                    wbase = e;
                    vidx  = sorted[wbase + lane];
                }
                const int k    = e - wbase;            // uniform, multiple of 8
                const int take = min(end - e, 64 - k); // multiple of 8
                for (int ii = 0; ii < take; ii += 8) {
                    int q0 = __builtin_amdgcn_readlane(vidx, k + ii + 0);
                    int q1 = __builtin_amdgcn_readlane(vidx, k + ii + 1);
                    int q2 = __builtin_amdgcn_readlane(vidx, k + ii + 2);
                    int q3 = __builtin_amdgcn_readlane(vidx, k + ii + 3);
                    int q4 = __builtin_amdgcn_readlane(vidx, k + ii + 4);
                    int q5 = __builtin_amdgcn_readlane(vidx, k + ii + 5);
                    int q6 = __builtin_amdgcn_readlane(vidx, k + ii + 6);
                    int q7 = __builtin_amdgcn_readlane(vidx, k + ii + 7);
                    unsigned short u0 = xb[(size_t)q0 * DD + lane];  // 8 in flight
                    unsigned short u1 = xb[(size_t)q1 * DD + lane];
                    unsigned short u2 = xb[(size_t)q2 * DD + lane];
                    unsigned short u3 = xb[(size_t)q3 * DD + lane];
                    unsigned short u4 = xb[(size_t)q4 * DD + lane];
                    unsigned short u5 = xb[(size_t)q5 * DD + lane];
                    unsigned short u6 = xb[(size_t)q6 * DD + lane];
                    unsigned short u7 = xb[(size_t)q7 * DD + lane];
                    const int base = e + ii;
                    while (base + 0 == next_b && r < RR) flush();
                    cur += bf2f(u0);
                    while (base + 1 == next_b && r < RR) flush();
                    cur += bf2f(u1);
                    while (base + 2 == next_b && r < RR) flush();
                    cur += bf2f(u2);
                    while (base + 3 == next_b && r < RR) flush();
                    cur += bf2f(u3);
                    while (base + 4 == next_b && r < RR) flush();
                    cur += bf2f(u4);
                    while (base + 5 == next_b && r < RR) flush();
                    cur += bf2f(u5);
                    while (base + 6 == next_b && r < RR) flush();
                    cur += bf2f(u6);
                    while (base + 7 == next_b && r < RR) flush();
                    cur += bf2f(u7);
                }
                e += take;
            }
            while (r < RR) flush();                    // drain (covers empties)

            ao[(8 * DD + lane) ^ xsh] = xb[(size_t)dst * DD + lane];  // x row
        }
    }

    __syncthreads();

    // ================= phase 2: MFMA from LDS A =================
    const int rlo = lane & 15;
    const int kg  = lane >> 4;
    const int cf  = wv;                            // 4 col frags (4x16 = 64)
    const int row = rlo;                           // single 16-row group
    const int xsh = (row & 7) << 3;

    f32x4 acc = {0.f,0.f,0.f,0.f};

    const unsigned short* arow = As + row * KA;
    #pragma unroll
    for (int t = 0; t < NT; ++t) {
        bf16x8 a = *(const bf16x8*)(arow + ((t * 32 + kg * 8) ^ xsh));
        bf16x8 b = *(const bf16x8*)(Bh + (size_t)t * 2048 + (size_t)cf * 512
                                       + lane * 8);
        acc = __builtin_amdgcn_mfma_f32_16x16x32_bf16(a, b, acc, 0, 0, 0);
    }

    // C/D layout: col = lane&15, row = (lane>>4)*4 + reg
    const float bl = bias[rlo + cf * 16];
    const int orow = nb + kg * 4;
    #pragma unroll
    for (int j = 0; j < 4; ++j) {
        int rr2 = orow + j;
        if (rr2 < N) out[(size_t)rr2 * DD + rlo + cf * 16] = acc[j] + bl;
    }
}

extern "C" void kernel_launch(void* const* d_in, const int* in_sizes, int n_in,
                              void* d_out, int out_size, void* d_ws, size_t ws_size,
                              hipStream_t stream)
{
    const float* x     = (const float*)d_in[0];
    const int*   ei    = (const int*)d_in[1];
    const int*   et    = (const int*)d_in[2];
    const float* Wrel  = (const float*)d_in[3];
    const float* Wroot = (const float*)d_in[4];
    const float* bias  = (const float*)d_in[5];

    const int N = in_sizes[0] / DD;
    const int E = in_sizes[2];
    const int M = N * RR;

    float* out    = (float*)d_out;
    float* out_ei = out + (size_t)N * DD;
    float* out_et = out_ei + (size_t)2 * E;

    auto align = [](size_t v) { return (v + 255) & ~(size_t)255; };

    const int nsb    = (E + ECH - 1) / ECH;          // count blocks
    const int nwaves = nsb * 4;                      // compaction waves
    const int ngrp   = (nwaves + 3) / 4;             // scatter groups

    // workspace layout
    size_t p = 0;
    int* cnt = (int*)((char*)d_ws + p);              p += align((size_t)M * 4);
    int* counter = (int*)((char*)d_ws + p);
    size_t zero_bytes = p + 256;                     p += 256;
    int* startv = (int*)((char*)d_ws + p);           p += align((size_t)N * 4);
    int* start2 = (int*)((char*)d_ws + p);           p += align((size_t)M * 4);
    unsigned long long* q = (unsigned long long*)((char*)d_ws + p);
    p += align((size_t)nwaves * NPART * SEGCAP * 8);
    int* qlen = (int*)((char*)d_ws + p);             p += align((size_t)nwaves * NPART * 4);
    int* sorted = (int*)((char*)d_ws + p);           p += align(((size_t)E + 7*(size_t)N + 128) * 4);
    unsigned short* xb = (unsigned short*)((char*)d_ws + p); p += align(((size_t)N + 1) * DD * 2);
    unsigned short* Bh = (unsigned short*)((char*)d_ws + p); p += align((size_t)NT*4*64*8*2);

    hipMemsetAsync(d_ws, 0, zero_bytes, stream);     // cnt + counter

    // partition magic: p = (dst * pmagic) >> 32 in [0, NPART)
    unsigned pmagic = (unsigned)((((unsigned long long)NPART << 32) + N - 1) / N);

    const int xblocks = ((N + 1) * (DD / 4) + 255) / 256;
    const int wblocks = (NT * 4 * 64 * 8 + 255) / 256;

    k_prep<<<dim3(xblocks + wblocks), 256, 0, stream>>>(
        x, xb, Wrel, Wroot, Bh, N, xblocks);
    k_count_rank_echo<<<dim3(nsb), 256, 0, stream>>>(
        ei, et, cnt, q, qlen, out_ei, out_et, E, pmagic);
    k_alloc<<<dim3((N + 255) / 256), 256, 0, stream>>>(
        cnt, startv, start2, counter, sorted, N);
    k_scatter_seg<<<dim3(ngrp * NPART), 256, 0, stream>>>(
        q, qlen, start2, sorted, nwaves);
    k_agg_mfma<<<dim3((N + TILE - 1) / TILE), 256, 0, stream>>>(
        xb, sorted, startv, cnt, Bh, bias, out, N);
}

// Round 18
// 189.033 us; speedup vs baseline: 1.1805x; 1.0222x over previous
//
#include <hip/hip_runtime.h>

#define DD 64          // node embedding dim
#define RR 8           // num relations
#define KA 576         // (RR+1)*DD : agg rows 0..7 + x as "relation 8"
#define NT 18          // K steps = KA/32
#define NPART 8        // dst partitions ~ XCDs (blockIdx%8 round-robin)
#define ECH 2048       // edges per block in count kernel
#define TILE 16        // dsts per fused block (18.4KB LDS -> 8 blocks/CU)
#define SEGCAP 160     // per-(wave,partition) segment capacity (mean 64, 12sigma)

typedef short bf16x8 __attribute__((ext_vector_type(8)));   // 8 bf16
typedef float f32x4  __attribute__((ext_vector_type(4)));

__device__ __forceinline__ float bf2f(unsigned short u) {
    union { unsigned u; float f; } c; c.u = ((unsigned)u) << 16; return c.f;
}
__device__ __forceinline__ unsigned short f2bf(float f) {
    union { float f; unsigned u; } c; c.f = f;
    unsigned u = c.u;
    u += 0x7FFF + ((u >> 16) & 1);      // round-to-nearest-even
    return (unsigned short)(u >> 16);
}

// ---------------------------------------------------------------------------
// FRONT kernel: heterogeneous block ranges.
//   [0, nsb)                : count + rank + echo + wave-local compaction
//   [nsb, nsb+xblocks)      : x -> bf16 cast (+ zero pad row N)
//   [nsb+xblocks, ...)      : pack Wcat into MFMA-B fragment order
// Count blocks dispatch first; prep streaming runs concurrently under the
// count's atomic-latency shadow. One launch + one gap removed.
// ---------------------------------------------------------------------------
__global__ __launch_bounds__(256) void k_front(
    const int* __restrict__ ei, const int* __restrict__ et,
    int* __restrict__ cnt, unsigned long long* __restrict__ q,
    int* __restrict__ qlen, float* __restrict__ out_ei,
    float* __restrict__ out_et, int E, unsigned pmagic,
    const float* __restrict__ x, unsigned short* __restrict__ xb,
    const float* __restrict__ Wrel, const float* __restrict__ Wroot,
    unsigned short* __restrict__ Bh, int N, int nsb, int xblocks)
{
    if ((int)blockIdx.x >= nsb) {
        int pb = (int)blockIdx.x - nsb;
        if (pb < xblocks) {
            // ---- xcast ----
            int i = pb * 256 + threadIdx.x;                  // quad index
            int total = (N + 1) * (DD / 4);
            if (i >= total) return;
            ushort4 o;
            if (i < N * (DD / 4)) {
                float4 f = ((const float4*)x)[i];
                o = make_ushort4(f2bf(f.x), f2bf(f.y), f2bf(f.z), f2bf(f.w));
            } else {
                o = make_ushort4(0, 0, 0, 0);
            }
            ((ushort4*)xb)[i] = o;
        } else {
            // ---- packW ----
            int idx = (pb - xblocks) * 256 + threadIdx.x;
            if (idx >= NT * 4 * 64 * 8) return;
            int i    = idx & 7;
            int lane = (idx >> 3) & 63;
            int f    = (idx >> 9) & 3;
            int t    = idx >> 11;
            int k = t * 32 + (lane >> 4) * 8 + i;
            int d = f * 16 + (lane & 15);
            int r = k >> 6, kk = k & 63;
            float w = (r < RR) ? Wrel[((size_t)r * DD + kk) * DD + d]
                               : Wroot[(size_t)kk * DD + d];
            Bh[idx] = f2bf(w);
        }
        return;
    }

    // ---- count + rank + echo + compaction ----
    const int base = blockIdx.x * ECH + threadIdx.x;
    const int lane = threadIdx.x & 63;
    const int gwid = blockIdx.x * 4 + (threadIdx.x >> 6);

    int d[8], t[8], s[8], rk[8]; bool m[8];
    #pragma unroll
    for (int j = 0; j < 8; ++j) {
        int e = base + j * 256;
        m[j] = (e < E);
        d[j] = m[j] ? ei[E + e] : 0;
    }
    #pragma unroll
    for (int j = 0; j < 8; ++j) {
        int e = base + j * 256;
        if (m[j]) { t[j] = et[e]; s[j] = ei[e]; }
    }
    #pragma unroll
    for (int j = 0; j < 8; ++j)
        if (m[j]) rk[j] = atomicAdd(&cnt[(size_t)d[j] * RR + t[j]], 1);
    #pragma unroll
    for (int j = 0; j < 8; ++j) {
        int e = base + j * 256;
        if (m[j]) {
            out_ei[e]     = (float)s[j];
            out_ei[E + e] = (float)d[j];
            out_et[e]     = (float)t[j];
        }
    }

    // compaction: partition tag p = mul_hi(dst, pmagic) in [0,7]
    int run0=0,run1=0,run2=0,run3=0,run4=0,run5=0,run6=0,run7=0;
    unsigned long long* qw = q + (size_t)gwid * NPART * SEGCAP;
    #pragma unroll
    for (int j = 0; j < 8; ++j) {
        int pj = m[j]
            ? (int)(((unsigned long long)(unsigned)d[j] * pmagic) >> 32)
            : -1;
        unsigned long long k0 = __ballot(pj == 0);
        unsigned long long k1 = __ballot(pj == 1);
        unsigned long long k2 = __ballot(pj == 2);
        unsigned long long k3 = __ballot(pj == 3);
        unsigned long long k4 = __ballot(pj == 4);
        unsigned long long k5 = __ballot(pj == 5);
        unsigned long long k6 = __ballot(pj == 6);
        unsigned long long k7 = __ballot(pj == 7);
        unsigned long long km =
            (pj==0)?k0:(pj==1)?k1:(pj==2)?k2:(pj==3)?k3:
            (pj==4)?k4:(pj==5)?k5:(pj==6)?k6:k7;
        int bb =
            (pj==0)?run0:(pj==1)?run1:(pj==2)?run2:(pj==3)?run3:
            (pj==4)?run4:(pj==5)?run5:(pj==6)?run6:run7;
        int off = __popcll(km & ((1ull << lane) - 1ull));
        if (pj >= 0 && bb + off < SEGCAP) {
            unsigned lo = (unsigned)s[j] | ((unsigned)t[j]  << 20);
            unsigned hi = (unsigned)d[j] | ((unsigned)rk[j] << 20);
            qw[(size_t)pj * SEGCAP + bb + off] =
                ((unsigned long long)hi << 32) | lo;
        }
        run0 += __popcll(k0); run1 += __popcll(k1);
        run2 += __popcll(k2); run3 += __popcll(k3);
        run4 += __popcll(k4); run5 += __popcll(k5);
        run6 += __popcll(k6); run7 += __popcll(k7);
    }
    if (lane == 0) {
        int* ql = qlen + (size_t)gwid * NPART;
        ql[0]=run0; ql[1]=run1; ql[2]=run2; ql[3]=run3;
        ql[4]=run4; ql[5]=run5; ql[6]=run6; ql[7]=run7;
    }
}

// ---------------------------------------------------------------------------
// Per-dst bucket allocation (padded to x8) + per-(dst,rel) cell starts, so
// scatter can compute positions WITHOUT atomics. Pads (src=N -> zero row)
// written after run 7.
// ---------------------------------------------------------------------------
__global__ __launch_bounds__(256) void k_alloc(
    const int* __restrict__ cnt, int* __restrict__ startv,
    int* __restrict__ start2, int* __restrict__ counter,
    int* __restrict__ sorted, int N)
{
    __shared__ int sdata[256];
    __shared__ int sbase;
    const int tid = threadIdx.x;
    const int n = blockIdx.x * 256 + tid;

    int deg = 0, deg8 = 0;
    int c[RR];
    if (n < N) {
        const int4* c4 = (const int4*)(cnt + (size_t)n * RR);
        int4 a = c4[0], b = c4[1];
        c[0]=a.x; c[1]=a.y; c[2]=a.z; c[3]=a.w;
        c[4]=b.x; c[5]=b.y; c[6]=b.z; c[7]=b.w;
        #pragma unroll
        for (int r = 0; r < RR; ++r) deg += c[r];
        deg8 = (deg + 7) & ~7;
    }
    sdata[tid] = deg8;
    __syncthreads();
    int v = deg8;
    #pragma unroll
    for (int off = 1; off < 256; off <<= 1) {
        int t = (tid >= off) ? sdata[tid - off] : 0;
        __syncthreads();
        v += t;
        sdata[tid] = v;
        __syncthreads();
    }
    if (tid == 255) sbase = atomicAdd(counter, v);
    __syncthreads();
    if (n < N) {
        int st = sbase + v - deg8;
        startv[n] = st;
        int h = st;
        #pragma unroll
        for (int r = 0; r < RR; ++r) { start2[(size_t)n * RR + r] = h; h += c[r]; }
        for (int j = deg; j < deg8; ++j) sorted[st + j] = N;   // pad -> zero row
    }
}

// ---------------------------------------------------------------------------
// Segment scatter: one wave per (wave,partition) segment, read-once.
// Block b = grp*8+p handles partition p only -> stores stay XCD-local.
// pos = start2[dst*8+rel] + rank; sorted[pos] = src. No atomics, no rescans.
// ---------------------------------------------------------------------------
__global__ __launch_bounds__(256) void k_scatter_seg(
    const unsigned long long* __restrict__ q, const int* __restrict__ qlen,
    const int* __restrict__ start2, int* __restrict__ sorted, int nwaves)
{
    const int p    = blockIdx.x & (NPART - 1);
    const int grp  = blockIdx.x / NPART;
    const int gwid = grp * 4 + (threadIdx.x >> 6);
    const int lane = threadIdx.x & 63;
    if (gwid >= nwaves) return;
    const int seg = gwid * NPART + p;
    const int len = qlen[seg];
    const unsigned long long* qs = q + (size_t)seg * SEGCAP;
    for (int i = lane; i < len; i += 64) {
        unsigned long long v = qs[i];
        int cell = (int)((v >> 32) & 0xFFFFFu) * RR + (int)((v >> 20) & 7u);
        int pos  = start2[cell] + (int)(v >> 52);
        sorted[pos] = (int)(v & 0xFFFFFu);
    }
}

// ---------------------------------------------------------------------------
// FUSED aggregate + transform (unchanged from round 16/17: ~80us).
// Block = 256 threads (4 waves), 16 dsts; LDS 18.4KB -> 8 blocks/CU.
// ---------------------------------------------------------------------------
__global__ __launch_bounds__(256) void k_agg_mfma(
    const unsigned short* __restrict__ xb, const int* __restrict__ sorted,
    const int* __restrict__ startv, const int* __restrict__ cnt,
    const unsigned short* __restrict__ Bh, const float* __restrict__ bias,
    float* __restrict__ out, int N)
{
    __shared__ __align__(16) unsigned short As[TILE * KA];   // 18432 B
    const int nb   = blockIdx.x * TILE;
    const int wv   = threadIdx.x >> 6;
    const int lane = threadIdx.x & 63;

    // ================= phase 1: aggregate 4 dsts per wave =================
    const int row0 = wv * 4;
    const int dst0 = nb + row0;
    const int nv   = min(4, N - dst0);
    if (nv > 0) {
        int cidx = lane & 31;
        if (cidx >= nv * 8) cidx = nv * 8 - 1;          // clamp (safety)
        const int cv = cnt[(size_t)dst0 * RR + cidx];
        int sidx = lane & 3;
        if (sidx >= nv) sidx = nv - 1;
        const int sv = startv[dst0 + sidx];

        for (int i = 0; i < 4; ++i) {
            if (i >= nv) break;                         // wave-uniform
            const int row = row0 + i;
            const int dst = dst0 + i;
            const int xsh = (row & 7) << 3;             // XOR swizzle (shorts)
            unsigned short* ao = As + row * KA;
            const int cb = i * 8;                       // uniform cnt base

            int deg = 0;
            #pragma unroll
            for (int r = 0; r < RR; ++r)
                deg += __builtin_amdgcn_readlane(cv, cb + r);
            const int deg8 = (deg + 7) & ~7;

            const int s0  = __builtin_amdgcn_readlane(sv, i);
            const int end = s0 + deg8;

            int   r      = 0;
            int   c_r    = __builtin_amdgcn_readlane(cv, cb);
            int   next_b = s0 + c_r;
            float cur    = 0.f;

            auto flush = [&]() {
                float inv = __builtin_amdgcn_rcpf(fmaxf((float)c_r, 1.f));
                ao[(r * DD + lane) ^ xsh] = f2bf(cur * inv);
                cur = 0.f;
                ++r;
                c_r = __builtin_amdgcn_readlane(cv, cb + (r & 7));
                next_b += c_r;
            };

            int e = s0;
            int wbase = s0;
            int vidx  = sorted[wbase + lane];
            while (e < end) {
                if (e - wbase >= 64) {                 // slide index window
                    wbase = e;
                    vidx  = sorted[wbase + lane];
                }
                const int k    = e - wbase;            // uniform, multiple of 8
                const int take = min(end - e, 64 - k); // multiple of 8
                for (int ii = 0; ii < take; ii += 8) {
                    int q0 = __builtin_amdgcn_readlane(vidx, k + ii + 0);
                    int q1 = __builtin_amdgcn_readlane(vidx, k + ii + 1);
                    int q2 = __builtin_amdgcn_readlane(vidx, k + ii + 2);
                    int q3 = __builtin_amdgcn_readlane(vidx, k + ii + 3);
                    int q4 = __builtin_amdgcn_readlane(vidx, k + ii + 4);
                    int q5 = __builtin_amdgcn_readlane(vidx, k + ii + 5);
                    int q6 = __builtin_amdgcn_readlane(vidx, k + ii + 6);
                    int q7 = __builtin_amdgcn_readlane(vidx, k + ii + 7);
                    unsigned short u0 = xb[(size_t)q0 * DD + lane];  // 8 in flight
                    unsigned short u1 = xb[(size_t)q1 * DD + lane];
                    unsigned short u2 = xb[(size_t)q2 * DD + lane];
                    unsigned short u3 = xb[(size_t)q3 * DD + lane];
                    unsigned short u4 = xb[(size_t)q4 * DD + lane];
                    unsigned short u5 = xb[(size_t)q5 * DD + lane];
                    unsigned short u6 = xb[(size_t)q6 * DD + lane];
                    unsigned short u7 = xb[(size_t)q7 * DD + lane];
                    const int base = e + ii;
                    while (base + 0 == next_b && r < RR) flush();
                    cur += bf2f(u0);
                    while (base + 1 == next_b && r < RR) flush();
                    cur += bf2f(u1);
                    while (base + 2 == next_b && r < RR) flush();
                    cur += bf2f(u2);
                    while (base + 3 == next_b && r < RR) flush();
                    cur += bf2f(u3);
                    while (base + 4 == next_b && r < RR) flush();
                    cur += bf2f(u4);
                    while (base + 5 == next_b && r < RR) flush();
                    cur += bf2f(u5);
                    while (base + 6 == next_b && r < RR) flush();
                    cur += bf2f(u6);
                    while (base + 7 == next_b && r < RR) flush();
                    cur += bf2f(u7);
                }
                e += take;
            }
            while (r < RR) flush();                    // drain (covers empties)

            ao[(8 * DD + lane) ^ xsh] = xb[(size_t)dst * DD + lane];  // x row
        }
    }

    __syncthreads();

    // ================= phase 2: MFMA from LDS A =================
    const int rlo = lane & 15;
    const int kg  = lane >> 4;
    const int cf  = wv;                            // 4 col frags (4x16 = 64)
    const int row = rlo;                           // single 16-row group
    const int xsh = (row & 7) << 3;

    f32x4 acc = {0.f,0.f,0.f,0.f};

    const unsigned short* arow = As + row * KA;
    #pragma unroll
    for (int t = 0; t < NT; ++t) {
        bf16x8 a = *(const bf16x8*)(arow + ((t * 32 + kg * 8) ^ xsh));
        bf16x8 b = *(const bf16x8*)(Bh + (size_t)t * 2048 + (size_t)cf * 512
                                       + lane * 8);
        acc = __builtin_amdgcn_mfma_f32_16x16x32_bf16(a, b, acc, 0, 0, 0);
    }

    // C/D layout: col = lane&15, row = (lane>>4)*4 + reg
    const float bl = bias[rlo + cf * 16];
    const int orow = nb + kg * 4;
    #pragma unroll
    for (int j = 0; j < 4; ++j) {
        int rr2 = orow + j;
        if (rr2 < N) out[(size_t)rr2 * DD + rlo + cf * 16] = acc[j] + bl;
    }
}

extern "C" void kernel_launch(void* const* d_in, const int* in_sizes, int n_in,
                              void* d_out, int out_size, void* d_ws, size_t ws_size,
                              hipStream_t stream)
{
    const float* x     = (const float*)d_in[0];
    const int*   ei    = (const int*)d_in[1];
    const int*   et    = (const int*)d_in[2];
    const float* Wrel  = (const float*)d_in[3];
    const float* Wroot = (const float*)d_in[4];
    const float* bias  = (const float*)d_in[5];

    const int N = in_sizes[0] / DD;
    const int E = in_sizes[2];
    const int M = N * RR;

    float* out    = (float*)d_out;
    float* out_ei = out + (size_t)N * DD;
    float* out_et = out_ei + (size_t)2 * E;

    auto align = [](size_t v) { return (v + 255) & ~(size_t)255; };

    const int nsb    = (E + ECH - 1) / ECH;          // count blocks
    const int nwaves = nsb * 4;                      // compaction waves
    const int ngrp   = (nwaves + 3) / 4;             // scatter groups

    // workspace layout
    size_t p = 0;
    int* cnt = (int*)((char*)d_ws + p);              p += align((size_t)M * 4);
    int* counter = (int*)((char*)d_ws + p);
    size_t zero_bytes = p + 256;                     p += 256;
    int* startv = (int*)((char*)d_ws + p);           p += align((size_t)N * 4);
    int* start2 = (int*)((char*)d_ws + p);           p += align((size_t)M * 4);
    unsigned long long* q = (unsigned long long*)((char*)d_ws + p);
    p += align((size_t)nwaves * NPART * SEGCAP * 8);
    int* qlen = (int*)((char*)d_ws + p);             p += align((size_t)nwaves * NPART * 4);
    int* sorted = (int*)((char*)d_ws + p);           p += align(((size_t)E + 7*(size_t)N + 128) * 4);
    unsigned short* xb = (unsigned short*)((char*)d_ws + p); p += align(((size_t)N + 1) * DD * 2);
    unsigned short* Bh = (unsigned short*)((char*)d_ws + p); p += align((size_t)NT*4*64*8*2);

    hipMemsetAsync(d_ws, 0, zero_bytes, stream);     // cnt + counter

    // partition magic: p = (dst * pmagic) >> 32 in [0, NPART)
    unsigned pmagic = (unsigned)((((unsigned long long)NPART << 32) + N - 1) / N);

    const int xblocks = ((N + 1) * (DD / 4) + 255) / 256;
    const int wblocks = (NT * 4 * 64 * 8 + 255) / 256;

    k_front<<<dim3(nsb + xblocks + wblocks), 256, 0, stream>>>(
        ei, et, cnt, q, qlen, out_ei, out_et, E, pmagic,
        x, xb, Wrel, Wroot, Bh, N, nsb, xblocks);
    k_alloc<<<dim3((N + 255) / 256), 256, 0, stream>>>(
        cnt, startv, start2, counter, sorted, N);
    k_scatter_seg<<<dim3(ngrp * NPART), 256, 0, stream>>>(
        q, qlen, start2, sorted, nwaves);
    k_agg_mfma<<<dim3((N + TILE - 1) / TILE), 256, 0, stream>>>(
        xb, sorted, startv, cnt, Bh, bias, out, N);
}